// Round 2
// baseline (1422.506 us; speedup 1.0000x reference)
//
#include <hip/hip_runtime.h>

#define N_NODES 100000
#define N_EDGES 1600000
#define IN_F    256
#define OUT_F   128

#define BROWS    64                       // rows per bucket
#define NB       1563                     // ceil(N_NODES / BROWS)
#define CAP      1312                     // slots/bucket (mean 1024, sigma 32 -> +9 sigma)
#define PART_EPB 8192

typedef __attribute__((ext_vector_type(8))) short   s16x8;   // 8 x bf16 (MFMA A/B frag)
typedef __attribute__((ext_vector_type(4))) float   f32x4;   // MFMA C/D frag
typedef __attribute__((ext_vector_type(8))) unsigned short u16x8;

__device__ __forceinline__ unsigned short f2bf(float f) {   // fp32 -> bf16 RNE
    unsigned u = __float_as_uint(f);
    u += 0x7FFFu + ((u >> 16) & 1u);
    return (unsigned short)(u >> 16);
}
__device__ __forceinline__ float bf2f(unsigned short h) {
    return __uint_as_float((unsigned)h << 16);
}

// LDS fp32 atomic add, workgroup scope -> native ds_add_f32 (NOT the global
// fadd path that unsafeAtomicAdd took last round: flat-aperture atomics
// serialized at ~200cy each = the whole 1190us regression).
#define LADD(slot, v) \
    __hip_atomic_fetch_add(&(slot), (v), __ATOMIC_RELAXED, __HIP_MEMORY_SCOPE_WORKGROUP)

// ---------------------------------------------------------------------------
// K0: Wt[n][k] = bf16(W[k][n])  + zero bucket cursors (fused: saves a launch)
// ---------------------------------------------------------------------------
__global__ __launch_bounds__(256) void wt_build(const float* __restrict__ W,
                                                unsigned short* __restrict__ Wt,
                                                int* __restrict__ cursor) {
    const int n = blockIdx.x;       // 0..127
    const int k = threadIdx.x;      // 0..255
    Wt[n * IN_F + k] = f2bf(W[(size_t)k * OUT_F + n]);
    const int idx = blockIdx.x * 256 + threadIdx.x;
    if (idx < NB) cursor[idx] = 0;
}

// ---------------------------------------------------------------------------
// K1: support_bf16[M,128] = bf16( X[M,256] @ W[256,128] ) via MFMA 16x16x32.
// Tile: 64 rows x 128 cols per block (4 waves, 16 rows/wave), BK=32.
// (unchanged from verified 322us version)
// ---------------------------------------------------------------------------
__global__ __launch_bounds__(256) void gemm_mfma(const float* __restrict__ X,
                                                 const unsigned short* __restrict__ Wt,
                                                 unsigned short* __restrict__ support) {
    __shared__ unsigned short As[64][40];    // [m][k], 80B rows (5x16B: aligned + staggered)
    __shared__ unsigned short Bs[128][40];   // [n][k]
    __shared__ unsigned short Ct[64][136];   // epilogue repack, 272B rows (17x16B)

    const int t    = threadIdx.x;
    const int wid  = t >> 6;
    const int lane = t & 63;
    const int tm   = lane & 15;
    const int quad = lane >> 4;
    const int row0 = blockIdx.x * 64;

    f32x4 acc[8];
#pragma unroll
    for (int c = 0; c < 8; ++c) acc[c] = (f32x4){0.f, 0.f, 0.f, 0.f};

    for (int kb = 0; kb < IN_F; kb += 32) {
        // stage A: 64 rows x 32 k fp32 -> bf16. thread: m=t>>2, k0=(t&3)*8
        {
            const int m  = t >> 2;
            const int k0 = (t & 3) * 8;
            const int gr = row0 + m;
            float4 x0 = make_float4(0.f, 0.f, 0.f, 0.f), x1 = x0;
            if (gr < N_NODES) {
                const float* xp = &X[(size_t)gr * IN_F + kb + k0];
                x0 = *(const float4*)xp;
                x1 = *(const float4*)(xp + 4);
            }
            ushort4 a0, a1;
            a0.x = f2bf(x0.x); a0.y = f2bf(x0.y); a0.z = f2bf(x0.z); a0.w = f2bf(x0.w);
            a1.x = f2bf(x1.x); a1.y = f2bf(x1.y); a1.z = f2bf(x1.z); a1.w = f2bf(x1.w);
            *(ushort4*)&As[m][k0]     = a0;
            *(ushort4*)&As[m][k0 + 4] = a1;
        }
        // stage B: 128 n x 32 k bf16 from Wt (two u16x8 writes = 16 shorts)
        {
            const int n  = t >> 1;
            const int k0 = (t & 1) * 16;
            const unsigned short* wp = &Wt[(size_t)n * IN_F + kb + k0];
            *(u16x8*)&Bs[n][k0]     = *(const u16x8*)wp;
            *(u16x8*)&Bs[n][k0 + 8] = *(const u16x8*)(wp + 8);
        }
        __syncthreads();

        const s16x8 a = *(const s16x8*)&As[wid * 16 + tm][quad * 8];
#pragma unroll
        for (int c = 0; c < 8; ++c) {
            const s16x8 b = *(const s16x8*)&Bs[c * 16 + tm][quad * 8];
            acc[c] = __builtin_amdgcn_mfma_f32_16x16x32_bf16(a, b, acc[c], 0, 0, 0);
        }
        __syncthreads();
    }

    // epilogue: regs -> LDS (bf16) -> coalesced global
#pragma unroll
    for (int c = 0; c < 8; ++c) {
        const int col = c * 16 + tm;
#pragma unroll
        for (int reg = 0; reg < 4; ++reg) {
            const int m = wid * 16 + quad * 4 + reg;
            Ct[m][col] = f2bf(acc[c][reg]);
        }
    }
    __syncthreads();
    {
        const int m   = t >> 2;
        const int seg = (t & 3) * 32;
        const int gr  = row0 + m;
        if (gr < N_NODES) {
            unsigned short* op = &support[(size_t)gr * OUT_F + seg];
#pragma unroll
            for (int i = 0; i < 4; ++i)
                *(u16x8*)(op + i * 8) = *(const u16x8*)&Ct[m][seg + i * 8];
        }
    }
}

// ---------------------------------------------------------------------------
// K2: partition edges into fixed-stride bucket regions (epackA, in ws).
// pack: .x = (rowlocal<<17) | col, .y = bits of val.   bucket = row >> 6.
// ---------------------------------------------------------------------------
__global__ __launch_bounds__(256) void partition_edges(const int* __restrict__ arow,
                                                       const int* __restrict__ acol,
                                                       const float* __restrict__ aval,
                                                       int* __restrict__ cursor,
                                                       int2* __restrict__ epackA) {
    __shared__ int cnt[NB];
    __shared__ int basep[NB];
    const int t = threadIdx.x;
    for (int k = t; k < NB; k += 256) cnt[k] = 0;
    __syncthreads();
    const int base = blockIdx.x * PART_EPB;
    const int lim  = min(base + PART_EPB, N_EDGES);
    for (int i = base + t; i < lim; i += 256) atomicAdd(&cnt[arow[i] >> 6], 1);
    __syncthreads();
    for (int k = t; k < NB; k += 256) {
        const int c = cnt[k];
        if (c > 0) basep[k] = atomicAdd(&cursor[k], c);
        cnt[k] = 0;
    }
    __syncthreads();
    for (int i = base + t; i < lim; i += 256) {
        const int r    = arow[i];
        const int b    = r >> 6;
        const int rank = atomicAdd(&cnt[b], 1);
        const int pos  = basep[b] + rank;
        if (pos < CAP)       // 9-sigma guard; never triggers for this input
            epackA[(size_t)b * CAP + pos] =
                make_int2(((r & (BROWS - 1)) << 17) | acol[i], __float_as_int(aval[i]));
    }
}

// ---------------------------------------------------------------------------
// K3: fused bucket SpMM.  Block per bucket: fp32 accumulator Ls in LDS (32KB,
// 5 blocks/CU).  8 groups of 32 lanes stream the unordered bucket edges.
//
// COLUMN-PERMUTED accumulator: feat f lives at col (f&1)*64 + (f>>1).
//   lane l's four atomic targets per edge: cols {l, 64+l, 32+l, 96+l}
//   -> bank l%32 for each instruction -> exactly 2 lanes/bank per wave64
//   -> conflict-free (m136: 2-way is free).  (Identity layout was 4-way.)
// Atomics are __hip_atomic_fetch_add WORKGROUP scope -> ds_add_f32.
// ---------------------------------------------------------------------------
__global__ __launch_bounds__(256) void bucket_spmm(const int* __restrict__ cursor,
                                                   const int2* __restrict__ epackA,
                                                   const unsigned short* __restrict__ support,
                                                   const float* __restrict__ bias,
                                                   float* __restrict__ out) {
    __shared__ float Ls[BROWS][OUT_F];   // 32 KB fp32 accumulator (permuted cols)

    const int b = blockIdx.x;
    const int t = threadIdx.x;
    const int g = t >> 5;        // group 0..7
    const int l = t & 31;        // lane in group

    // zero accumulator: 8192 floats / 256 threads = 8 float4 each
    {
        const int f4  = (t & 31) * 4;
        const int rl0 = t >> 5;
#pragma unroll
        for (int p = 0; p < 8; ++p)
            *(float4*)&Ls[rl0 + p * 8][f4] = make_float4(0.f, 0.f, 0.f, 0.f);
    }
    __syncthreads();

    const int s = b * CAP;
    const int n = min(cursor[b], CAP);
    // contiguous chunk per group, rounded to 4 so int4 loads stay 16B-aligned
    const int chunk = (((n + 7) >> 3) + 3) & ~3;
    int i = g * chunk;
    const int hi = min(n, i + chunk);

    for (; i + 4 <= hi; i += 4) {
        const int4 p01 = *(const int4*)&epackA[(size_t)s + i];      // edges i, i+1
        const int4 p23 = *(const int4*)&epackA[(size_t)s + i + 2];  // edges i+2, i+3
        const int c0 = p01.x & 0x1FFFF, c1 = p01.z & 0x1FFFF;
        const int c2 = p23.x & 0x1FFFF, c3 = p23.z & 0x1FFFF;
        // issue all 8 support loads before any atomic (MLP)
        const ushort2 a0 = *(const ushort2*)&support[(size_t)c0 * OUT_F + 2 * l];
        const ushort2 b0 = *(const ushort2*)&support[(size_t)c0 * OUT_F + 64 + 2 * l];
        const ushort2 a1 = *(const ushort2*)&support[(size_t)c1 * OUT_F + 2 * l];
        const ushort2 b1 = *(const ushort2*)&support[(size_t)c1 * OUT_F + 64 + 2 * l];
        const ushort2 a2 = *(const ushort2*)&support[(size_t)c2 * OUT_F + 2 * l];
        const ushort2 b2 = *(const ushort2*)&support[(size_t)c2 * OUT_F + 64 + 2 * l];
        const ushort2 a3 = *(const ushort2*)&support[(size_t)c3 * OUT_F + 2 * l];
        const ushort2 b3 = *(const ushort2*)&support[(size_t)c3 * OUT_F + 64 + 2 * l];
        const float v0 = __int_as_float(p01.y), v1 = __int_as_float(p01.w);
        const float v2 = __int_as_float(p23.y), v3 = __int_as_float(p23.w);
        const int r0 = p01.x >> 17, r1 = p01.z >> 17;
        const int r2 = p23.x >> 17, r3 = p23.z >> 17;
        // feat 2l -> col l ; feat 2l+1 -> col 64+l ; feat 64+2l -> col 32+l ;
        // feat 64+2l+1 -> col 96+l
        LADD(Ls[r0][l],      v0 * bf2f(a0.x));
        LADD(Ls[r0][64 + l], v0 * bf2f(a0.y));
        LADD(Ls[r0][32 + l], v0 * bf2f(b0.x));
        LADD(Ls[r0][96 + l], v0 * bf2f(b0.y));
        LADD(Ls[r1][l],      v1 * bf2f(a1.x));
        LADD(Ls[r1][64 + l], v1 * bf2f(a1.y));
        LADD(Ls[r1][32 + l], v1 * bf2f(b1.x));
        LADD(Ls[r1][96 + l], v1 * bf2f(b1.y));
        LADD(Ls[r2][l],      v2 * bf2f(a2.x));
        LADD(Ls[r2][64 + l], v2 * bf2f(a2.y));
        LADD(Ls[r2][32 + l], v2 * bf2f(b2.x));
        LADD(Ls[r2][96 + l], v2 * bf2f(b2.y));
        LADD(Ls[r3][l],      v3 * bf2f(a3.x));
        LADD(Ls[r3][64 + l], v3 * bf2f(a3.y));
        LADD(Ls[r3][32 + l], v3 * bf2f(b3.x));
        LADD(Ls[r3][96 + l], v3 * bf2f(b3.y));
    }
    for (; i < hi; ++i) {
        const int2 e = epackA[(size_t)s + i];
        const int  c = e.x & 0x1FFFF;
        const int  r = e.x >> 17;
        const float v = __int_as_float(e.y);
        const ushort2 ua = *(const ushort2*)&support[(size_t)c * OUT_F + 2 * l];
        const ushort2 ub = *(const ushort2*)&support[(size_t)c * OUT_F + 64 + 2 * l];
        LADD(Ls[r][l],      v * bf2f(ua.x));
        LADD(Ls[r][64 + l], v * bf2f(ua.y));
        LADD(Ls[r][32 + l], v * bf2f(ub.x));
        LADD(Ls[r][96 + l], v * bf2f(ub.y));
    }
    __syncthreads();

    // epilogue: un-permute + bias, float4 coalesced store.
    // output feats {4j,4j+1,4j+2,4j+3} = cols {2j, 64+2j, 2j+1, 64+2j+1}
    {
        const int j   = t & 31;      // feature quad index
        const int rl0 = t >> 5;
        const float4 bv = *(const float4*)&bias[4 * j];
#pragma unroll
        for (int p = 0; p < 8; ++p) {
            const int rl = rl0 + p * 8;
            const int r  = b * BROWS + rl;
            if (r < N_NODES) {
                const float2 lo = *(const float2*)&Ls[rl][2 * j];        // feats 4j, 4j+2
                const float2 hi = *(const float2*)&Ls[rl][64 + 2 * j];   // feats 4j+1, 4j+3
                float4 acc;
                acc.x = lo.x + bv.x;
                acc.y = hi.x + bv.y;
                acc.z = lo.y + bv.z;
                acc.w = hi.y + bv.w;
                *(float4*)&out[(size_t)r * OUT_F + 4 * j] = acc;
            }
        }
    }
}

// ---------------------------------------------------------------------------
extern "C" void kernel_launch(void* const* d_in, const int* in_sizes, int n_in,
                              void* d_out, int out_size, void* d_ws, size_t ws_size,
                              hipStream_t stream) {
    const float* X    = (const float*)d_in[0];
    const int*   arow = (const int*)d_in[1];
    const int*   acol = (const int*)d_in[2];
    const float* aval = (const float*)d_in[3];
    const float* W    = (const float*)d_in[4];
    const float* bias = (const float*)d_in[5];
    float*       out  = (float*)d_out;

    // ws: support bf16 (25.6MB) | Wt bf16 (64KB) | cursor[NB] (6.3KB)
    //     | epackA int2[NB*CAP] (16.4MB)               total ~42.08MB
    char* ws = (char*)d_ws;
    unsigned short* support = (unsigned short*)ws;  ws += (size_t)N_NODES * OUT_F * 2;
    unsigned short* Wt = (unsigned short*)ws;       ws += (size_t)IN_F * OUT_F * 2;
    int*   cursor  = (int*)ws;                      ws += ((NB + 7) & ~7) * 4;
    int2*  epackA  = (int2*)ws;

    wt_build<<<OUT_F, 256, 0, stream>>>(W, Wt, cursor);
    gemm_mfma<<<(N_NODES + 63) / 64, 256, 0, stream>>>(X, Wt, support);
    partition_edges<<<(N_EDGES + PART_EPB - 1) / PART_EPB, 256, 0, stream>>>(
        arow, acol, aval, cursor, epackA);
    bucket_spmm<<<NB, 256, 0, stream>>>(cursor, epackA, support, bias, out);
}

// Round 3
// 437.150 us; speedup vs baseline: 3.2540x; 3.2540x over previous
//
#include <hip/hip_runtime.h>

#define N_NODES 100000
#define N_EDGES 1600000
#define IN_F    256
#define OUT_F   128

#define NPAD      100352                  // 98 * 1024 (scan padding)
#define SCAN_NBLK 98
#define HIST_EPB  4096

typedef __attribute__((ext_vector_type(8))) short   s16x8;   // 8 x bf16 (MFMA A/B frag)
typedef __attribute__((ext_vector_type(4))) float   f32x4;   // MFMA C/D frag
typedef __attribute__((ext_vector_type(8))) unsigned short u16x8;

__device__ __forceinline__ unsigned short f2bf(float f) {   // fp32 -> bf16 RNE
    unsigned u = __float_as_uint(f);
    u += 0x7FFFu + ((u >> 16) & 1u);
    return (unsigned short)(u >> 16);
}
__device__ __forceinline__ float bf2f(unsigned short h) {
    return __uint_as_float((unsigned)h << 16);
}

// ---------------------------------------------------------------------------
// K0: Wt[n][k] = bf16(W[k][n])  + zero row histogram (incl. scan pad)
// ---------------------------------------------------------------------------
__global__ __launch_bounds__(256) void wt_build(const float* __restrict__ W,
                                                unsigned short* __restrict__ Wt,
                                                int* __restrict__ rowcnt) {
    const int n = blockIdx.x;       // 0..127
    const int k = threadIdx.x;      // 0..255
    Wt[n * IN_F + k] = f2bf(W[(size_t)k * OUT_F + n]);
    for (int i = blockIdx.x * 256 + threadIdx.x; i < NPAD; i += OUT_F * 256)
        rowcnt[i] = 0;
}

// ---------------------------------------------------------------------------
// K1: support_bf16[M,128] = bf16( X[M,256] @ W[256,128] ) via MFMA 16x16x32.
// (unchanged from verified 322us version)
// ---------------------------------------------------------------------------
__global__ __launch_bounds__(256) void gemm_mfma(const float* __restrict__ X,
                                                 const unsigned short* __restrict__ Wt,
                                                 unsigned short* __restrict__ support) {
    __shared__ unsigned short As[64][40];    // [m][k], 80B rows (5x16B: aligned + staggered)
    __shared__ unsigned short Bs[128][40];   // [n][k]
    __shared__ unsigned short Ct[64][136];   // epilogue repack, 272B rows (17x16B)

    const int t    = threadIdx.x;
    const int wid  = t >> 6;
    const int lane = t & 63;
    const int tm   = lane & 15;
    const int quad = lane >> 4;
    const int row0 = blockIdx.x * 64;

    f32x4 acc[8];
#pragma unroll
    for (int c = 0; c < 8; ++c) acc[c] = (f32x4){0.f, 0.f, 0.f, 0.f};

    for (int kb = 0; kb < IN_F; kb += 32) {
        // stage A: 64 rows x 32 k fp32 -> bf16. thread: m=t>>2, k0=(t&3)*8
        {
            const int m  = t >> 2;
            const int k0 = (t & 3) * 8;
            const int gr = row0 + m;
            float4 x0 = make_float4(0.f, 0.f, 0.f, 0.f), x1 = x0;
            if (gr < N_NODES) {
                const float* xp = &X[(size_t)gr * IN_F + kb + k0];
                x0 = *(const float4*)xp;
                x1 = *(const float4*)(xp + 4);
            }
            ushort4 a0, a1;
            a0.x = f2bf(x0.x); a0.y = f2bf(x0.y); a0.z = f2bf(x0.z); a0.w = f2bf(x0.w);
            a1.x = f2bf(x1.x); a1.y = f2bf(x1.y); a1.z = f2bf(x1.z); a1.w = f2bf(x1.w);
            *(ushort4*)&As[m][k0]     = a0;
            *(ushort4*)&As[m][k0 + 4] = a1;
        }
        // stage B: 128 n x 32 k bf16 from Wt (two u16x8 writes = 16 shorts)
        {
            const int n  = t >> 1;
            const int k0 = (t & 1) * 16;
            const unsigned short* wp = &Wt[(size_t)n * IN_F + kb + k0];
            *(u16x8*)&Bs[n][k0]     = *(const u16x8*)wp;
            *(u16x8*)&Bs[n][k0 + 8] = *(const u16x8*)(wp + 8);
        }
        __syncthreads();

        const s16x8 a = *(const s16x8*)&As[wid * 16 + tm][quad * 8];
#pragma unroll
        for (int c = 0; c < 8; ++c) {
            const s16x8 b = *(const s16x8*)&Bs[c * 16 + tm][quad * 8];
            acc[c] = __builtin_amdgcn_mfma_f32_16x16x32_bf16(a, b, acc[c], 0, 0, 0);
        }
        __syncthreads();
    }

    // epilogue: regs -> LDS (bf16) -> coalesced global
#pragma unroll
    for (int c = 0; c < 8; ++c) {
        const int col = c * 16 + tm;
#pragma unroll
        for (int reg = 0; reg < 4; ++reg) {
            const int m = wid * 16 + quad * 4 + reg;
            Ct[m][col] = f2bf(acc[c][reg]);
        }
    }
    __syncthreads();
    {
        const int m   = t >> 2;
        const int seg = (t & 3) * 32;
        const int gr  = row0 + m;
        if (gr < N_NODES) {
            unsigned short* op = &support[(size_t)gr * OUT_F + seg];
#pragma unroll
            for (int i = 0; i < 4; ++i)
                *(u16x8*)(op + i * 8) = *(const u16x8*)&Ct[m][seg + i * 8];
        }
    }
}

// ---------------------------------------------------------------------------
// K2: row histogram via global (L2-side) int atomics. 1.6M atomics total —
// ~6K/CU, cheap. (DS atomics measured at ~3.6 cyc/LANE r1/r2 — never again.)
// ---------------------------------------------------------------------------
__global__ __launch_bounds__(256) void hist(const int* __restrict__ arow,
                                            int* __restrict__ rowcnt) {
    const int base = blockIdx.x * HIST_EPB;
    const int lim  = min(base + HIST_EPB, N_EDGES);
    for (int i = base + threadIdx.x; i < lim; i += 256)
        atomicAdd(&rowcnt[arow[i]], 1);
}

// ---------------------------------------------------------------------------
// K3a: per-block (1024-elem) exclusive scan -> tmp, block totals -> btot
// ---------------------------------------------------------------------------
__global__ __launch_bounds__(256) void scan1(const int* __restrict__ rowcnt,
                                             int* __restrict__ tmp,
                                             int* __restrict__ btot) {
    __shared__ int wsum[4];
    const int t  = threadIdx.x;
    const int i0 = blockIdx.x * 1024 + t * 4;
    const int4 v = *(const int4*)&rowcnt[i0];      // pad zeroed by wt_build
    const int tsum = v.x + v.y + v.z + v.w;
    const int lane = t & 63;
    int x = tsum;
#pragma unroll
    for (int off = 1; off < 64; off <<= 1) {
        const int y = __shfl_up(x, off, 64);
        if (lane >= off) x += y;
    }
    if (lane == 63) wsum[t >> 6] = x;
    __syncthreads();
    int pre = x - tsum;                 // exclusive within wave
    const int w = t >> 6;
    for (int k = 0; k < w; ++k) pre += wsum[k];
    int4 o;
    o.x = pre;
    o.y = pre + v.x;
    o.z = o.y + v.y;
    o.w = o.z + v.z;
    *(int4*)&tmp[i0] = o;
    if (t == 255) btot[blockIdx.x] = pre + tsum;
}

// ---------------------------------------------------------------------------
// K3b: scan of 98 block totals (single 128-thread block, Hillis-Steele)
// ---------------------------------------------------------------------------
__global__ __launch_bounds__(128) void scan2(const int* __restrict__ btot,
                                             int* __restrict__ boffs) {
    __shared__ int s[128];
    const int t  = threadIdx.x;
    const int my = (t < SCAN_NBLK) ? btot[t] : 0;
    s[t] = my;
    __syncthreads();
    for (int off = 1; off < 128; off <<= 1) {
        const int add = (t >= off) ? s[t - off] : 0;
        __syncthreads();
        s[t] += add;
        __syncthreads();
    }
    if (t < SCAN_NBLK) boffs[t] = s[t] - my;   // exclusive
}

// ---------------------------------------------------------------------------
// K3c: finalize rowmeta{start,deg} + cursor = start
// ---------------------------------------------------------------------------
__global__ __launch_bounds__(256) void scan3(const int* __restrict__ rowcnt,
                                             const int* __restrict__ tmp,
                                             const int* __restrict__ boffs,
                                             int2* __restrict__ rowmeta,
                                             int* __restrict__ cursor) {
    const int t  = threadIdx.x;
    const int i0 = blockIdx.x * 1024 + t * 4;
    const int bo = boffs[blockIdx.x];
    const int4 v = *(const int4*)&rowcnt[i0];
    const int4 p = *(const int4*)&tmp[i0];
    const int4 st = make_int4(p.x + bo, p.y + bo, p.z + bo, p.w + bo);
    *(int4*)&cursor[i0] = st;                      // cursor is NPAD-sized: safe
    if (i0 + 3 < N_NODES) {
        const int4 m0 = make_int4(st.x, v.x, st.y, v.y);
        const int4 m1 = make_int4(st.z, v.z, st.w, v.w);
        *(int4*)&rowmeta[i0]     = m0;
        *(int4*)&rowmeta[i0 + 2] = m1;
    } else {
        const int sa[4] = {st.x, st.y, st.z, st.w};
        const int va[4] = {v.x, v.y, v.z, v.w};
        for (int j = 0; j < 4; ++j)
            if (i0 + j < N_NODES) rowmeta[i0 + j] = make_int2(sa[j], va[j]);
    }
}

// ---------------------------------------------------------------------------
// K4: scatter edges into exact CSR order. Order within a row irrelevant (sum).
// ---------------------------------------------------------------------------
__global__ __launch_bounds__(256) void scatter_edges(const int* __restrict__ arow,
                                                     const int* __restrict__ acol,
                                                     const float* __restrict__ aval,
                                                     int* __restrict__ cursor,
                                                     int2* __restrict__ epackB) {
    const int base = blockIdx.x * HIST_EPB;
    const int lim  = min(base + HIST_EPB, N_EDGES);
    for (int i = base + threadIdx.x; i < lim; i += 256) {
        const int r   = arow[i];
        const int pos = atomicAdd(&cursor[r], 1);
        epackB[pos] = make_int2(acol[i], __float_as_int(aval[i]));
    }
}

// ---------------------------------------------------------------------------
// K5: CSR gather (bf16 support) — 32 lanes/row, lane owns 4 feats, 4-edge ILP.
// out[r] = bias + sum val * support[col]   (fp32 accumulate)
// (byte-for-byte the verified 322us-version kernel)
// ---------------------------------------------------------------------------
__global__ __launch_bounds__(256) void csr_gather(const int2* __restrict__ rowmeta,
                                                  const int2* __restrict__ epackB,
                                                  const unsigned short* __restrict__ support,
                                                  const float* __restrict__ bias,
                                                  float* __restrict__ out) {
    const int t = threadIdx.x;
    const int g = t >> 5;
    const int l = t & 31;
    const int r = blockIdx.x * 8 + g;
    if (r >= N_NODES) return;

    const int2 rm   = rowmeta[r];
    const int start = rm.x;
    const int deg   = rm.y;

    float4 acc = *(const float4*)&bias[l * 4];

    int i = 0;
    for (; i + 4 <= deg; i += 4) {
        const int2 e0 = epackB[start + i + 0];
        const int2 e1 = epackB[start + i + 1];
        const int2 e2 = epackB[start + i + 2];
        const int2 e3 = epackB[start + i + 3];
        const ushort4 u0 = *(const ushort4*)&support[(size_t)e0.x * OUT_F + l * 4];
        const ushort4 u1 = *(const ushort4*)&support[(size_t)e1.x * OUT_F + l * 4];
        const ushort4 u2 = *(const ushort4*)&support[(size_t)e2.x * OUT_F + l * 4];
        const ushort4 u3 = *(const ushort4*)&support[(size_t)e3.x * OUT_F + l * 4];
        const float v0 = __int_as_float(e0.y);
        const float v1 = __int_as_float(e1.y);
        const float v2 = __int_as_float(e2.y);
        const float v3 = __int_as_float(e3.y);
        acc.x = fmaf(v0, bf2f(u0.x), fmaf(v1, bf2f(u1.x), fmaf(v2, bf2f(u2.x), fmaf(v3, bf2f(u3.x), acc.x))));
        acc.y = fmaf(v0, bf2f(u0.y), fmaf(v1, bf2f(u1.y), fmaf(v2, bf2f(u2.y), fmaf(v3, bf2f(u3.y), acc.y))));
        acc.z = fmaf(v0, bf2f(u0.z), fmaf(v1, bf2f(u1.z), fmaf(v2, bf2f(u2.z), fmaf(v3, bf2f(u3.z), acc.z))));
        acc.w = fmaf(v0, bf2f(u0.w), fmaf(v1, bf2f(u1.w), fmaf(v2, bf2f(u2.w), fmaf(v3, bf2f(u3.w), acc.w))));
    }
    for (; i < deg; ++i) {
        const int2 e = epackB[start + i];
        const ushort4 u = *(const ushort4*)&support[(size_t)e.x * OUT_F + l * 4];
        const float v = __int_as_float(e.y);
        acc.x = fmaf(v, bf2f(u.x), acc.x);
        acc.y = fmaf(v, bf2f(u.y), acc.y);
        acc.z = fmaf(v, bf2f(u.z), acc.z);
        acc.w = fmaf(v, bf2f(u.w), acc.w);
    }

    *(float4*)&out[(size_t)r * OUT_F + l * 4] = acc;
}

// ---------------------------------------------------------------------------
extern "C" void kernel_launch(void* const* d_in, const int* in_sizes, int n_in,
                              void* d_out, int out_size, void* d_ws, size_t ws_size,
                              hipStream_t stream) {
    const float* X    = (const float*)d_in[0];
    const int*   arow = (const int*)d_in[1];
    const int*   acol = (const int*)d_in[2];
    const float* aval = (const float*)d_in[3];
    const float* W    = (const float*)d_in[4];
    const float* bias = (const float*)d_in[5];
    float*       out  = (float*)d_out;

    // ws: support bf16 25.6MB | Wt 64KB | rowcnt/tmp/cursor int[NPAD] 3x401KB
    //     | btot/boffs 2x512B | rowmeta int2[N] 800KB | epackB int2[E] 12.8MB
    //     total ~40.5MB  (epackA gone; epackB exact-size, no CAP slack)
    char* ws = (char*)d_ws;
    unsigned short* support = (unsigned short*)ws;  ws += (size_t)N_NODES * OUT_F * 2;
    unsigned short* Wt = (unsigned short*)ws;       ws += (size_t)IN_F * OUT_F * 2;
    int*  rowcnt  = (int*)ws;                       ws += (size_t)NPAD * 4;
    int*  tmp     = (int*)ws;                       ws += (size_t)NPAD * 4;
    int*  cursor  = (int*)ws;                       ws += (size_t)NPAD * 4;
    int*  btot    = (int*)ws;                       ws += 128 * 4;
    int*  boffs   = (int*)ws;                       ws += 128 * 4;
    int2* rowmeta = (int2*)ws;                      ws += (size_t)N_NODES * 8;
    int2* epackB  = (int2*)ws;

    wt_build<<<OUT_F, 256, 0, stream>>>(W, Wt, rowcnt);
    gemm_mfma<<<(N_NODES + 63) / 64, 256, 0, stream>>>(X, Wt, support);
    hist<<<(N_EDGES + HIST_EPB - 1) / HIST_EPB, 256, 0, stream>>>(arow, rowcnt);
    scan1<<<SCAN_NBLK, 256, 0, stream>>>(rowcnt, tmp, btot);
    scan2<<<1, 128, 0, stream>>>(btot, boffs);
    scan3<<<SCAN_NBLK, 256, 0, stream>>>(rowcnt, tmp, boffs, rowmeta, cursor);
    scatter_edges<<<(N_EDGES + HIST_EPB - 1) / HIST_EPB, 256, 0, stream>>>(
        arow, acol, aval, cursor, epackB);
    csr_gather<<<(N_NODES + 7) / 8, 256, 0, stream>>>(
        rowmeta, epackB, support, bias, out);
}

// Round 5
// 289.431 us; speedup vs baseline: 4.9148x; 1.5104x over previous
//
#include <hip/hip_runtime.h>

#define N_NODES 100000
#define N_EDGES 1600000
#define IN_F    256
#define OUT_F   128

#define BROWS2   256                  // rows per coarse bucket
#define NB2      391                  // ceil(N_NODES / 256)
#define CAPB     4800                 // slots/bucket (mean 4096, sigma 64 -> +11 sigma)
#define PART_EPB 4096                 // edges per partition block (391 blocks)
#define KE       (PART_EPB / 256)     // 16 edges/thread in partition
#define KB       ((CAPB + 255) / 256) // 19 edges/thread in bucket_build

typedef __attribute__((ext_vector_type(8))) short   s16x8;   // 8 x bf16 (MFMA A/B frag)
typedef __attribute__((ext_vector_type(4))) float   f32x4;   // MFMA C/D frag
typedef __attribute__((ext_vector_type(8))) unsigned short u16x8;

__device__ __forceinline__ unsigned short f2bf(float f) {   // fp32 -> bf16 RNE
    unsigned u = __float_as_uint(f);
    u += 0x7FFFu + ((u >> 16) & 1u);
    return (unsigned short)(u >> 16);
}
__device__ __forceinline__ float bf2f(unsigned short h) {
    return __uint_as_float((unsigned)h << 16);
}

// ---------------------------------------------------------------------------
// K0: Wt[n][k] = bf16(W[k][n])  + zero bucket cursors
// ---------------------------------------------------------------------------
__global__ __launch_bounds__(256) void wt_build(const float* __restrict__ W,
                                                unsigned short* __restrict__ Wt,
                                                int* __restrict__ cursorA) {
    const int n = blockIdx.x;       // 0..127
    const int k = threadIdx.x;      // 0..255
    Wt[n * IN_F + k] = f2bf(W[(size_t)k * OUT_F + n]);
    const int idx = blockIdx.x * 256 + threadIdx.x;
    if (idx < NB2) cursorA[idx] = 0;
}

// ---------------------------------------------------------------------------
// K1: support_bf16[M,128] = bf16( X[M,256] @ W[256,128] ) via MFMA 16x16x32.
// (unchanged from verified version)
// ---------------------------------------------------------------------------
__global__ __launch_bounds__(256) void gemm_mfma(const float* __restrict__ X,
                                                 const unsigned short* __restrict__ Wt,
                                                 unsigned short* __restrict__ support) {
    __shared__ unsigned short As[64][40];    // [m][k], 80B rows (5x16B: aligned + staggered)
    __shared__ unsigned short Bs[128][40];   // [n][k]
    __shared__ unsigned short Ct[64][136];   // epilogue repack, 272B rows (17x16B)

    const int t    = threadIdx.x;
    const int wid  = t >> 6;
    const int lane = t & 63;
    const int tm   = lane & 15;
    const int quad = lane >> 4;
    const int row0 = blockIdx.x * 64;

    f32x4 acc[8];
#pragma unroll
    for (int c = 0; c < 8; ++c) acc[c] = (f32x4){0.f, 0.f, 0.f, 0.f};

    for (int kb = 0; kb < IN_F; kb += 32) {
        // stage A: 64 rows x 32 k fp32 -> bf16. thread: m=t>>2, k0=(t&3)*8
        {
            const int m  = t >> 2;
            const int k0 = (t & 3) * 8;
            const int gr = row0 + m;
            float4 x0 = make_float4(0.f, 0.f, 0.f, 0.f), x1 = x0;
            if (gr < N_NODES) {
                const float* xp = &X[(size_t)gr * IN_F + kb + k0];
                x0 = *(const float4*)xp;
                x1 = *(const float4*)(xp + 4);
            }
            ushort4 a0, a1;
            a0.x = f2bf(x0.x); a0.y = f2bf(x0.y); a0.z = f2bf(x0.z); a0.w = f2bf(x0.w);
            a1.x = f2bf(x1.x); a1.y = f2bf(x1.y); a1.z = f2bf(x1.z); a1.w = f2bf(x1.w);
            *(ushort4*)&As[m][k0]     = a0;
            *(ushort4*)&As[m][k0 + 4] = a1;
        }
        // stage B: 128 n x 32 k bf16 from Wt (two u16x8 writes = 16 shorts)
        {
            const int n  = t >> 1;
            const int k0 = (t & 1) * 16;
            const unsigned short* wp = &Wt[(size_t)n * IN_F + kb + k0];
            *(u16x8*)&Bs[n][k0]     = *(const u16x8*)wp;
            *(u16x8*)&Bs[n][k0 + 8] = *(const u16x8*)(wp + 8);
        }
        __syncthreads();

        const s16x8 a = *(const s16x8*)&As[wid * 16 + tm][quad * 8];
#pragma unroll
        for (int c = 0; c < 8; ++c) {
            const s16x8 b = *(const s16x8*)&Bs[c * 16 + tm][quad * 8];
            acc[c] = __builtin_amdgcn_mfma_f32_16x16x32_bf16(a, b, acc[c], 0, 0, 0);
        }
        __syncthreads();
    }

    // epilogue: regs -> LDS (bf16) -> coalesced global
#pragma unroll
    for (int c = 0; c < 8; ++c) {
        const int col = c * 16 + tm;
#pragma unroll
        for (int reg = 0; reg < 4; ++reg) {
            const int m = wid * 16 + quad * 4 + reg;
            Ct[m][col] = f2bf(acc[c][reg]);
        }
    }
    __syncthreads();
    {
        const int m   = t >> 2;
        const int seg = (t & 3) * 32;
        const int gr  = row0 + m;
        if (gr < N_NODES) {
            unsigned short* op = &support[(size_t)gr * OUT_F + seg];
#pragma unroll
            for (int i = 0; i < 4; ++i)
                *(u16x8*)(op + i * 8) = *(const u16x8*)&Ct[m][seg + i * 8];
        }
    }
}

// ---------------------------------------------------------------------------
// K2: partition edges into 391 coarse buckets (256 rows each), block-contiguous
// run allocation -> near-full-line writes (fix for r3's 8x write amplification:
// scatter_edges wrote 100MB HBM for a 12.8MB payload, 134us).
// ONE LDS atomic per edge; rank/payload carried in statically-indexed regs.
// pack: .x = (rowlocal<<17) | col, .y = val bits.   bucket = row >> 8.
// ---------------------------------------------------------------------------
__global__ __launch_bounds__(256) void partition_edges(const int* __restrict__ arow,
                                                       const int* __restrict__ acol,
                                                       const float* __restrict__ aval,
                                                       int* __restrict__ cursorA,
                                                       int2* __restrict__ epackA) {
    __shared__ int cnt[NB2];
    __shared__ int basep[NB2];
    const int t = threadIdx.x;
    for (int k = t; k < NB2; k += 256) cnt[k] = 0;
    __syncthreads();

    const int base = blockIdx.x * PART_EPB;
    int pk_[KE], vv_[KE], b_[KE], rk_[KE];
#pragma unroll
    for (int k = 0; k < KE; ++k) {
        const int i = base + t + k * 256;
        b_[k] = -1;
        if (i < N_EDGES) {
            const int r = arow[i];
            b_[k]  = r >> 8;
            pk_[k] = ((r & (BROWS2 - 1)) << 17) | acol[i];
            vv_[k] = __float_as_int(aval[i]);
            rk_[k] = atomicAdd(&cnt[b_[k]], 1);       // LDS, 1 per edge
        }
    }
    __syncthreads();
    for (int k = t; k < NB2; k += 256) {
        const int c = cnt[k];
        if (c > 0) basep[k] = atomicAdd(&cursorA[k], c);   // global, ~NB2/block
    }
    __syncthreads();
#pragma unroll
    for (int k = 0; k < KE; ++k) {
        if (b_[k] >= 0) {
            const int pos = basep[b_[k]] + rk_[k];
            if (pos < CAPB)      // 11-sigma guard
                epackA[(size_t)b_[k] * CAPB + pos] = make_int2(pk_[k], vv_[k]);
        }
    }
}

// ---------------------------------------------------------------------------
// K3: per-bucket exact CSR build. One block per bucket: LDS 256-row histogram
// (1 LDS atomic/edge, rank in regs), wave scan, rowmeta{start,deg}, ranked
// rewrite into epackB. Destination window = one bucket (~38KB) -> L2-resident,
// full-line covered -> no HBM write amplification. No global scan needed:
// epackB stays bucket-strided, rowmeta.start absorbs it.
// ---------------------------------------------------------------------------
__global__ __launch_bounds__(256) void bucket_build(const int* __restrict__ cursorA,
                                                    const int2* __restrict__ epackA,
                                                    int2* __restrict__ rowmeta,
                                                    int2* __restrict__ epackB) {
    __shared__ int cnt[BROWS2];
    __shared__ int excl[BROWS2];
    __shared__ int wsum[4];
    const int b = blockIdx.x;
    const int t = threadIdx.x;
    cnt[t] = 0;
    __syncthreads();

    const size_t sa = (size_t)b * CAPB;
    const int n = min(cursorA[b], CAPB);

    int pk_[KB], vv_[KB], rk_[KB];
#pragma unroll
    for (int k = 0; k < KB; ++k) {
        const int i = t + k * 256;
        rk_[k] = -1;
        if (i < n) {
            const int2 e = epackA[sa + i];
            pk_[k] = e.x;
            vv_[k] = e.y;
            rk_[k] = atomicAdd(&cnt[e.x >> 17], 1);   // LDS, 1 per edge
        }
    }
    __syncthreads();

    // exclusive scan of cnt[256] (4 waves: wave shfl-scan + wave-total combine)
    {
        const int lane = t & 63;
        const int my   = cnt[t];
        int x = my;
#pragma unroll
        for (int off = 1; off < 64; off <<= 1) {
            const int y = __shfl_up(x, off, 64);
            if (lane >= off) x += y;
        }
        if (lane == 63) wsum[t >> 6] = x;
        __syncthreads();
        int pre = x - my;
        const int w = t >> 6;
        for (int kk = 0; kk < w; ++kk) pre += wsum[kk];
        excl[t] = pre;
        const int r = b * BROWS2 + t;
        if (r < N_NODES) rowmeta[r] = make_int2((int)sa + pre, my);
    }
    __syncthreads();

#pragma unroll
    for (int k = 0; k < KB; ++k) {
        if (rk_[k] >= 0) {
            const int rl  = pk_[k] >> 17;
            const int pos = excl[rl] + rk_[k];
            epackB[sa + pos] = make_int2(pk_[k] & 0x1FFFF, vv_[k]);
        }
    }
}

// ---------------------------------------------------------------------------
// K4: CSR gather (bf16 support) — 32 lanes/row, lane owns 4 feats, 4-edge ILP.
// out[r] = bias + sum val * support[col]   (fp32 accumulate)
// (byte-for-byte the verified 322us-version kernel)
// ---------------------------------------------------------------------------
__global__ __launch_bounds__(256) void csr_gather(const int2* __restrict__ rowmeta,
                                                  const int2* __restrict__ epackB,
                                                  const unsigned short* __restrict__ support,
                                                  const float* __restrict__ bias,
                                                  float* __restrict__ out) {
    const int t = threadIdx.x;
    const int g = t >> 5;
    const int l = t & 31;
    const int r = blockIdx.x * 8 + g;
    if (r >= N_NODES) return;

    const int2 rm   = rowmeta[r];
    const int start = rm.x;
    const int deg   = rm.y;

    float4 acc = *(const float4*)&bias[l * 4];

    int i = 0;
    for (; i + 4 <= deg; i += 4) {
        const int2 e0 = epackB[start + i + 0];
        const int2 e1 = epackB[start + i + 1];
        const int2 e2 = epackB[start + i + 2];
        const int2 e3 = epackB[start + i + 3];
        const ushort4 u0 = *(const ushort4*)&support[(size_t)e0.x * OUT_F + l * 4];
        const ushort4 u1 = *(const ushort4*)&support[(size_t)e1.x * OUT_F + l * 4];
        const ushort4 u2 = *(const ushort4*)&support[(size_t)e2.x * OUT_F + l * 4];
        const ushort4 u3 = *(const ushort4*)&support[(size_t)e3.x * OUT_F + l * 4];
        const float v0 = __int_as_float(e0.y);
        const float v1 = __int_as_float(e1.y);
        const float v2 = __int_as_float(e2.y);
        const float v3 = __int_as_float(e3.y);
        acc.x = fmaf(v0, bf2f(u0.x), fmaf(v1, bf2f(u1.x), fmaf(v2, bf2f(u2.x), fmaf(v3, bf2f(u3.x), acc.x))));
        acc.y = fmaf(v0, bf2f(u0.y), fmaf(v1, bf2f(u1.y), fmaf(v2, bf2f(u2.y), fmaf(v3, bf2f(u3.y), acc.y))));
        acc.z = fmaf(v0, bf2f(u0.z), fmaf(v1, bf2f(u1.z), fmaf(v2, bf2f(u2.z), fmaf(v3, bf2f(u3.z), acc.z))));
        acc.w = fmaf(v0, bf2f(u0.w), fmaf(v1, bf2f(u1.w), fmaf(v2, bf2f(u2.w), fmaf(v3, bf2f(u3.w), acc.w))));
    }
    for (; i < deg; ++i) {
        const int2 e = epackB[start + i];
        const ushort4 u = *(const ushort4*)&support[(size_t)e.x * OUT_F + l * 4];
        const float v = __int_as_float(e.y);
        acc.x = fmaf(v, bf2f(u.x), acc.x);
        acc.y = fmaf(v, bf2f(u.y), acc.y);
        acc.z = fmaf(v, bf2f(u.z), acc.z);
        acc.w = fmaf(v, bf2f(u.w), acc.w);
    }

    *(float4*)&out[(size_t)r * OUT_F + l * 4] = acc;
}

// ---------------------------------------------------------------------------
extern "C" void kernel_launch(void* const* d_in, const int* in_sizes, int n_in,
                              void* d_out, int out_size, void* d_ws, size_t ws_size,
                              hipStream_t stream) {
    const float* X    = (const float*)d_in[0];
    const int*   arow = (const int*)d_in[1];
    const int*   acol = (const int*)d_in[2];
    const float* aval = (const float*)d_in[3];
    const float* W    = (const float*)d_in[4];
    const float* bias = (const float*)d_in[5];
    float*       out  = (float*)d_out;

    // ws: support bf16 25.6MB | Wt 64KB | rowmeta int2[N] 800KB | cursorA 1.6KB
    //     | epackB int2[NB2*CAPB] 15.0MB        total ~41.5MB
    // epackA (15.0MB) lives in d_out (51.2MB): consumed by bucket_build before
    // csr_gather rewrites out.
    char* ws = (char*)d_ws;
    unsigned short* support = (unsigned short*)ws;  ws += (size_t)N_NODES * OUT_F * 2;
    unsigned short* Wt = (unsigned short*)ws;       ws += (size_t)IN_F * OUT_F * 2;
    int2* rowmeta = (int2*)ws;                      ws += (size_t)N_NODES * 8;
    int*  cursorA = (int*)ws;                       ws += ((NB2 + 7) & ~7) * 4;
    int2* epackB  = (int2*)ws;
    int2* epackA  = (int2*)d_out;

    wt_build<<<OUT_F, 256, 0, stream>>>(W, Wt, cursorA);
    gemm_mfma<<<(N_NODES + 63) / 64, 256, 0, stream>>>(X, Wt, support);
    partition_edges<<<(N_EDGES + PART_EPB - 1) / PART_EPB, 256, 0, stream>>>(
        arow, acol, aval, cursorA, epackA);
    bucket_build<<<NB2, 256, 0, stream>>>(cursorA, epackA, rowmeta, epackB);
    csr_gather<<<(N_NODES + 7) / 8, 256, 0, stream>>>(
        rowmeta, epackB, support, bias, out);
}